// Round 3
// baseline (385.634 us; speedup 1.0000x reference)
//
#include <hip/hip_runtime.h>
#include <hip/hip_bf16.h>
#include <stdint.h>

// Problem: B=16, S=2048, I=1024, H=1024  (all fp32 in/out)
// out[b,s,h] = tanh( sum_i x[b,s,i]*W_ih[h,i] + b_ih[h] + sum_k hx[b,k]*W_hh[h,k] + b_hh[h] )
// M = B*S = 32768, N = H = 1024, K = I = 1024.
//
// v3: fused fp32->bf16 A-conversion + XCD-corrected mapping (kept) + NEW:
// 2-iteration prefetch depth everywhere. Triple-buffered LDS (3x16KB), B's
// global_load_lds issued 2 iters ahead (retired by vmcnt(10) one iter after
// issue, consumed the iter after that), A fp32 reg-loads issued 2 iters before
// their cvt->ds_write (which happens at ITER START, so lgkmcnt(0) at the
// barrier sees old ds_writes). Steady-state queue at each barrier:
// [A(T+3)x4, B(T+2)x2, A(T+4)x4] = 10 -> vmcnt(10) retires exactly B(T+1).
// Round-2 lesson: 1-iter prefetch < L3 latency (X is L3-resident, ~600cy);
// every counted wait was still blocking.

#define M_TOT 32768
#define N_TOT 1024
#define K_TOT 1024

typedef short short8 __attribute__((ext_vector_type(8)));   // 8 bf16 (4 VGPRs)
typedef float f32x4  __attribute__((ext_vector_type(4)));   // 4 fp32 acc

// ---- workspace layout (bytes) ----
#define WS_WBF_OFF 0          // W_bf: 1048576 bf16 = 2 MB
#define WS_HT_OFF  2097152    // h_term: 16384 fp32

__device__ __forceinline__ unsigned short f32_to_bf16_rne(float f) {
    union { float f; unsigned int u; } v; v.f = f;
    unsigned int u = v.u;
    unsigned int r = u + 0x7fffu + ((u >> 16) & 1u);
    return (unsigned short)(r >> 16);
}

__device__ __forceinline__ unsigned int cvt_pk_bf16(float lo, float hi) {
    unsigned int r;
    asm("v_cvt_pk_bf16_f32 %0, %1, %2" : "=v"(r) : "v"(lo), "v"(hi));
    return r;
}

__device__ __forceinline__ float fast_tanh(float z) {
    float e = __expf(2.0f * z);
    return 1.0f - 2.0f / (e + 1.0f);
}

// ---------------- kernel 1: prep = h_term + W_ih fp32->bf16 ----------------
__global__ void prep_kernel(const float* __restrict__ hx,
                            const float* __restrict__ whh,
                            const float* __restrict__ bih,
                            const float* __restrict__ bhh,
                            const float* __restrict__ wih,
                            float* __restrict__ ht,
                            unsigned short* __restrict__ wbf) {
    if (blockIdx.x < 4096) {
        int lane = threadIdx.x & 63;
        int w    = threadIdx.x >> 6;
        int wg   = blockIdx.x * 4 + w;        // 0..16383
        int b = wg >> 10, h = wg & 1023;
        const float* hr = hx  + (long long)b * 1024;
        const float* wr = whh + (long long)h * 1024;
        float s = 0.f;
#pragma unroll
        for (int p = 0; p < 4; ++p) {
            int idx = p * 256 + lane * 4;
            float4 a = *(const float4*)(hr + idx);
            float4 c = *(const float4*)(wr + idx);
            s += a.x * c.x + a.y * c.y + a.z * c.z + a.w * c.w;
        }
#pragma unroll
        for (int d = 32; d > 0; d >>= 1) s += __shfl_down(s, d, 64);
        if (lane == 0) ht[wg] = s + bih[h] + bhh[h];
    } else {
        int g = (blockIdx.x - 4096) * 256 + threadIdx.x;   // 0..32767
        for (int v = g; v < 131072; v += 32768) {
            long long base = (long long)v * 8;
            float4 a = *(const float4*)(wih + base);
            float4 b = *(const float4*)(wih + base + 4);
            union { unsigned short s[8]; uint4 u; } o;
            o.s[0] = f32_to_bf16_rne(a.x); o.s[1] = f32_to_bf16_rne(a.y);
            o.s[2] = f32_to_bf16_rne(a.z); o.s[3] = f32_to_bf16_rne(a.w);
            o.s[4] = f32_to_bf16_rne(b.x); o.s[5] = f32_to_bf16_rne(b.y);
            o.s[6] = f32_to_bf16_rne(b.z); o.s[7] = f32_to_bf16_rne(b.w);
            *(uint4*)(wbf + base) = o.u;
        }
    }
}

// ---------------- kernel 2: fused convert + bf16 MFMA GEMM + tanh ----------------
// 128x128 tile, BK=32, 256 threads = 4 waves in 2x2, each wave 64x64.
// LDS: THREE buffers, 16 KB each: buf i at [i*16384): A [0,8192) B [8192,16384).
#define GLDS16(gp, lp) \
    __builtin_amdgcn_global_load_lds((const __attribute__((address_space(1))) void*)(gp), \
                                     (__attribute__((address_space(3))) void*)(lp), 16, 0, 0)

// One K-iteration at index T. CURx = named reg set (T&1) holding A(T+2) fp32.
// bufC/bufW = runtime byte offsets of compute buffer (T%3) / write buffer ((T+2)%3).
#define KITER(T, CUR0, CUR1, CUR2, CUR3)                                       \
  {                                                                            \
    /* 1. B(T+2) -> bufB[(T+2)%3]; that buf was consumed at iter T-1 */        \
    const int kb = (((T) + 2) & 31) * 32;                                      \
    GLDS16(gB0 + kb, ldsB0 + bufW);                                            \
    GLDS16(gB1 + kb, ldsB1 + bufW);                                            \
    __builtin_amdgcn_sched_barrier(0);                                         \
    /* 2. cvt A(T+2) (loaded at iter T-2: 2-iter cover) -> bufA[(T+2)%3] */    \
    {                                                                          \
      uint4 pk0, pk1;                                                          \
      pk0.x = cvt_pk_bf16(CUR0.x, CUR0.y); pk0.y = cvt_pk_bf16(CUR0.z, CUR0.w);\
      pk0.z = cvt_pk_bf16(CUR1.x, CUR1.y); pk0.w = cvt_pk_bf16(CUR1.z, CUR1.w);\
      pk1.x = cvt_pk_bf16(CUR2.x, CUR2.y); pk1.y = cvt_pk_bf16(CUR2.z, CUR2.w);\
      pk1.z = cvt_pk_bf16(CUR3.x, CUR3.y); pk1.w = cvt_pk_bf16(CUR3.z, CUR3.w);\
      *(uint4*)(lA0 + bufW) = pk0;                                             \
      *(uint4*)(lA1 + bufW) = pk1;                                             \
    }                                                                          \
    __builtin_amdgcn_sched_barrier(0);                                         \
    /* 3. issue A(T+4) into the just-freed reg set (2-iter cover) */           \
    const int ka = (((T) + 4) & 31) * 32;                                      \
    CUR0 = *(const float4*)(gA + ka + 0);                                      \
    CUR1 = *(const float4*)(gA + ka + 4);                                      \
    CUR2 = *(const float4*)(gA + ka + 8);                                      \
    CUR3 = *(const float4*)(gA + ka + 12);                                     \
    __builtin_amdgcn_sched_barrier(0);                                         \
    /* 4. fragments from buf[T%3] + 16 MFMA */                                 \
    {                                                                          \
      const char* lb = lds + bufC;                                             \
      short8 af[4], bfr[4];                                                    \
      _Pragma("unroll")                                                        \
      for (int t4 = 0; t4 < 4; ++t4) {                                         \
        af[t4]  = *(const short8*)(lb + offA[t4]);                             \
        bfr[t4] = *(const short8*)(lb + offB[t4]);                             \
      }                                                                        \
      _Pragma("unroll")                                                        \
      for (int mt = 0; mt < 4; ++mt)                                           \
        _Pragma("unroll")                                                      \
        for (int nt = 0; nt < 4; ++nt)                                         \
          acc[mt][nt] = __builtin_amdgcn_mfma_f32_16x16x32_bf16(               \
              af[mt], bfr[nt], acc[mt][nt], 0, 0, 0);                          \
    }                                                                          \
    /* 5. vmcnt(10): steady queue is [A(T+3)4, B(T+2)2, A(T+4)4] -> retires    \
       exactly B(T+1) (issued 2 iters ago). lgkm: ds_writes are 1 region old. */\
    __builtin_amdgcn_sched_barrier(0);                                         \
    asm volatile("s_waitcnt vmcnt(10)" ::: "memory");                          \
    asm volatile("s_waitcnt lgkmcnt(0)" ::: "memory");                         \
    __builtin_amdgcn_s_barrier();                                              \
    __builtin_amdgcn_sched_barrier(0);                                         \
    bufC = (bufC == 32768) ? 0 : bufC + 16384;                                 \
    bufW = (bufW == 32768) ? 0 : bufW + 16384;                                 \
  }

__global__ __launch_bounds__(256) void gemm_tanh_kernel(
    const float* __restrict__ X,            // [32768,1024] fp32
    const unsigned short* __restrict__ Bm,  // [1024,1024]  bf16 (W_ih)
    const float* __restrict__ ht,           // [16,1024]
    float* __restrict__ out)                // [32768,1024] fp32
{
    __shared__ __align__(16) char lds[49152];

    const int tid = threadIdx.x;
    const int w = tid >> 6, l = tid & 63;

    // XCD-corrected mapping (verified: FETCH 265->90 MB).
    const int bid  = blockIdx.x;
    const int widx = (bid & 7) * 256 + (bid >> 3);
    const int tile_m = widx >> 3;      // 0..255
    const int tile_n = widx & 7;       // 0..7
    const int m0 = tile_m << 7, n0 = tile_n << 7;

    // ---- A staging (reg-staged fp32 -> cvt -> ds_write, XOR chunk swizzle) ----
    const int rowA  = tid >> 1;
    const int halfA = tid & 1;
    const float* gA = X + (long long)(m0 + rowA) * K_TOT + halfA * 16;
    const int swzA = (rowA >> 1) & 3;
    char* lA0 = lds + rowA * 64 + (((halfA * 2 + 0 + swzA) & 3) << 4);
    char* lA1 = lds + rowA * 64 + (((halfA * 2 + 1 + swzA) & 3) << 4);

    // ---- B staging (global_load_lds, inverse swizzle on global addr) ----
    const int r0 = (w * 2 + 0) * 16 + (l >> 2);
    const int r1 = (w * 2 + 1) * 16 + (l >> 2);
    const int slot = l & 3;
    const int qg0 = (slot - (r0 >> 1)) & 3;
    const int qg1 = (slot - (r1 >> 1)) & 3;
    const unsigned short* gB0 = Bm + (long long)(n0 + r0) * K_TOT + qg0 * 8;
    const unsigned short* gB1 = Bm + (long long)(n0 + r1) * K_TOT + qg1 * 8;
    char* ldsB0 = lds + 8192 + (w * 2 + 0) * 1024;
    char* ldsB1 = lds + 8192 + (w * 2 + 1) * 1024;

    // ---- fragment read offsets (within one 16 KB buffer) ----
    const int wm = w & 1, wn = w >> 1;
    const int lm = l & 15, q = l >> 4;
    int offA[4], offB[4];
#pragma unroll
    for (int t = 0; t < 4; ++t) {
        int rr = wm * 64 + t * 16 + lm;
        offA[t] = rr * 64 + (((q + (rr >> 1)) & 3) << 4);
        int nn = wn * 64 + t * 16 + lm;
        offB[t] = 8192 + nn * 64 + (((q + (nn >> 1)) & 3) << 4);
    }

    f32x4 acc[4][4];
#pragma unroll
    for (int i = 0; i < 4; ++i)
#pragma unroll
        for (int j = 0; j < 4; ++j)
            acc[i][j] = (f32x4){0.f, 0.f, 0.f, 0.f};

    // Two named A-register sets (rule #20). Set e = even iters, o = odd iters.
    float4 e0, e1, e2, e3;
    float4 o0, o1, o2, o3;

    // ---- prologue ----
    // B(0) -> buf0, B(1) -> buf1
    GLDS16(gB0 +  0, ldsB0);         GLDS16(gB1 +  0, ldsB1);
    GLDS16(gB0 + 32, ldsB0 + 16384); GLDS16(gB1 + 32, ldsB1 + 16384);
    __builtin_amdgcn_sched_barrier(0);
    // A(0) -> set e -> bufA0  (implicit wait also retires B(0),B(1): prologue only)
    e0 = *(const float4*)(gA + 0);  e1 = *(const float4*)(gA + 4);
    e2 = *(const float4*)(gA + 8);  e3 = *(const float4*)(gA + 12);
    {
        uint4 pk0, pk1;
        pk0.x = cvt_pk_bf16(e0.x, e0.y); pk0.y = cvt_pk_bf16(e0.z, e0.w);
        pk0.z = cvt_pk_bf16(e1.x, e1.y); pk0.w = cvt_pk_bf16(e1.z, e1.w);
        pk1.x = cvt_pk_bf16(e2.x, e2.y); pk1.y = cvt_pk_bf16(e2.z, e2.w);
        pk1.z = cvt_pk_bf16(e3.x, e3.y); pk1.w = cvt_pk_bf16(e3.z, e3.w);
        *(uint4*)lA0 = pk0;  *(uint4*)lA1 = pk1;
    }
    // A(1) -> set o -> bufA1
    o0 = *(const float4*)(gA + 32); o1 = *(const float4*)(gA + 36);
    o2 = *(const float4*)(gA + 40); o3 = *(const float4*)(gA + 44);
    {
        uint4 pk0, pk1;
        pk0.x = cvt_pk_bf16(o0.x, o0.y); pk0.y = cvt_pk_bf16(o0.z, o0.w);
        pk0.z = cvt_pk_bf16(o1.x, o1.y); pk0.w = cvt_pk_bf16(o1.z, o1.w);
        pk1.x = cvt_pk_bf16(o2.x, o2.y); pk1.y = cvt_pk_bf16(o2.z, o2.w);
        pk1.z = cvt_pk_bf16(o3.x, o3.y); pk1.w = cvt_pk_bf16(o3.z, o3.w);
        *(uint4*)(lA0 + 16384) = pk0;  *(uint4*)(lA1 + 16384) = pk1;
    }
    __builtin_amdgcn_sched_barrier(0);
    // A(2) -> set e, A(3) -> set o  (this order establishes the steady queue)
    e0 = *(const float4*)(gA + 64); e1 = *(const float4*)(gA + 68);
    e2 = *(const float4*)(gA + 72); e3 = *(const float4*)(gA + 76);
    o0 = *(const float4*)(gA + 96); o1 = *(const float4*)(gA + 100);
    o2 = *(const float4*)(gA + 104); o3 = *(const float4*)(gA + 108);
    __builtin_amdgcn_sched_barrier(0);
    asm volatile("s_waitcnt lgkmcnt(0)" ::: "memory");
    __builtin_amdgcn_s_barrier();
    __builtin_amdgcn_sched_barrier(0);

    int bufC = 0;        // (T  )%3 * 16384
    int bufW = 32768;    // (T+2)%3 * 16384

    // ---- main loop: 32 K-iters, unrolled x2 for register-set parity ----
    for (int tt = 0; tt < 32; tt += 2) {
        KITER(tt,     e0, e1, e2, e3);
        KITER(tt + 1, o0, o1, o2, o3);
    }
    // drain wrap prefetches so no GLDS lands in LDS after endpgm
    asm volatile("s_waitcnt vmcnt(0)" ::: "memory");

    // ---- epilogue: out = tanh(acc + h_term[b, n]) ----
    // C/D layout: col = lane&15 (n), row = (lane>>4)*4 + reg (m).
    const int b = tile_m >> 4;
    float htv[4];
#pragma unroll
    for (int nt = 0; nt < 4; ++nt)
        htv[nt] = ht[b * 1024 + n0 + wn * 64 + nt * 16 + lm];

#pragma unroll
    for (int mt = 0; mt < 4; ++mt) {
#pragma unroll
        for (int nt = 0; nt < 4; ++nt) {
            int n = n0 + wn * 64 + nt * 16 + lm;
#pragma unroll
            for (int r = 0; r < 4; ++r) {
                int m = m0 + wm * 64 + mt * 16 + q * 4 + r;
                float z = acc[mt][nt][r] + htv[nt];
                out[(long long)m * N_TOT + n] = fast_tanh(z);
            }
        }
    }
}

extern "C" void kernel_launch(void* const* d_in, const int* in_sizes, int n_in,
                              void* d_out, int out_size, void* d_ws, size_t ws_size,
                              hipStream_t stream) {
    const float* x    = (const float*)d_in[0];   // [16,2048,1024]
    const float* hx   = (const float*)d_in[1];   // [16,1024]
    const float* wih  = (const float*)d_in[2];   // [1024,1024]
    const float* whh  = (const float*)d_in[3];   // [1024,1024]
    const float* bih  = (const float*)d_in[4];   // [1024]
    const float* bhh  = (const float*)d_in[5];   // [1024]
    float* out = (float*)d_out;

    unsigned short* wbf = (unsigned short*)((char*)d_ws + WS_WBF_OFF);
    float*          htp = (float*)((char*)d_ws + WS_HT_OFF);

    prep_kernel<<<4224, 256, 0, stream>>>(hx, whh, bih, bhh, wih, htp, wbf);
    gemm_tanh_kernel<<<2048, 256, 0, stream>>>(x, wbf, htp, out);
}

// Round 5
// 330.762 us; speedup vs baseline: 1.1659x; 1.1659x over previous
//
#include <hip/hip_runtime.h>
#include <hip/hip_bf16.h>
#include <stdint.h>

// Problem: B=16, S=2048, I=1024, H=1024  (all fp32 in/out)
// out[b,s,h] = tanh( sum_i x[b,s,i]*W_ih[h,i] + b_ih[h] + sum_k hx[b,k]*W_hh[h,k] + b_hh[h] )
// M = B*S = 32768, N = H = 1024, K = I = 1024.
//
// v4 (resubmit after infra failure): round-0 skeleton (GLDS both operands,
// plain __syncthreads, compiler-scheduled) + XCD-corrected mapping (verified
// FETCH 265->90 MB) + single prep launch + BK=64 (32 KB LDS, 16 K-iters ->
// half as many barrier vmcnt(0) drains, 32 MFMA amortizing each).

#define M_TOT 32768
#define N_TOT 1024
#define K_TOT 1024

typedef short short8 __attribute__((ext_vector_type(8)));   // 8 bf16 (4 VGPRs)
typedef float f32x4  __attribute__((ext_vector_type(4)));   // 4 fp32 acc

// ---- workspace layout (bytes) ----
// [0, 67108864)            X_bf   : 33554432 bf16
// [67108864, 69206016)     W_bf   : 1048576 bf16
// [69206016, 69271552)     h_term : 16384 fp32
#define WS_XBF_OFF   0
#define WS_WBF_OFF   67108864
#define WS_HT_OFF    69206016

__device__ __forceinline__ unsigned short f32_to_bf16_rne(float f) {
    union { float f; unsigned int u; } v; v.f = f;
    unsigned int u = v.u;
    unsigned int r = u + 0x7fffu + ((u >> 16) & 1u);
    return (unsigned short)(r >> 16);
}

__device__ __forceinline__ float fast_tanh(float z) {
    // tanh(z) = 1 - 2/(exp(2z)+1); __expf -> v_exp_f32. Saturates at +-inf.
    float e = __expf(2.0f * z);
    return 1.0f - 2.0f / (e + 1.0f);
}

// ---------------- kernel 1: prep = X/W convert + h_term, one launch ----------------
// blocks [0, 2048): grid-stride fp32->bf16 convert of X then W_ih
// blocks [2048, 4096): h_term; each wave does 2 dot products (16384 total)
__global__ void prep_kernel(const float* __restrict__ x,
                            const float* __restrict__ wih,
                            const float* __restrict__ hx,
                            const float* __restrict__ whh,
                            const float* __restrict__ bih,
                            const float* __restrict__ bhh,
                            unsigned short* __restrict__ xbf,
                            unsigned short* __restrict__ wbf,
                            float* __restrict__ ht) {
    if (blockIdx.x < 2048) {
        const int NXV = 33554432 / 8;  // vec8 groups in X
        const int NWV = 1048576 / 8;   // vec8 groups in W_ih
        const int stride = 2048 * 256;
        for (int v = blockIdx.x * 256 + threadIdx.x; v < NXV + NWV; v += stride) {
            const float* src; unsigned short* dst; long long base;
            if (v < NXV) { src = x;   dst = xbf; base = (long long)v * 8; }
            else         { src = wih; dst = wbf; base = (long long)(v - NXV) * 8; }
            float4 a = *(const float4*)(src + base);
            float4 b = *(const float4*)(src + base + 4);
            union { unsigned short s[8]; uint4 u; } o;
            o.s[0] = f32_to_bf16_rne(a.x); o.s[1] = f32_to_bf16_rne(a.y);
            o.s[2] = f32_to_bf16_rne(a.z); o.s[3] = f32_to_bf16_rne(a.w);
            o.s[4] = f32_to_bf16_rne(b.x); o.s[5] = f32_to_bf16_rne(b.y);
            o.s[6] = f32_to_bf16_rne(b.z); o.s[7] = f32_to_bf16_rne(b.w);
            *(uint4*)(dst + base) = o.u;
        }
    } else {
        int lane = threadIdx.x & 63;
        int w    = threadIdx.x >> 6;
        int wg_base = (blockIdx.x - 2048) * 8 + w * 2;
#pragma unroll
        for (int d = 0; d < 2; ++d) {
            int wg = wg_base + d;                 // 0..16383
            int b = wg >> 10, h = wg & 1023;
            const float* hr = hx  + (long long)b * 1024;
            const float* wr = whh + (long long)h * 1024;
            float s = 0.f;
#pragma unroll
            for (int p = 0; p < 4; ++p) {
                int idx = p * 256 + lane * 4;
                float4 a = *(const float4*)(hr + idx);
                float4 c = *(const float4*)(wr + idx);
                s += a.x * c.x + a.y * c.y + a.z * c.z + a.w * c.w;
            }
#pragma unroll
            for (int dd = 32; dd > 0; dd >>= 1) s += __shfl_down(s, dd, 64);
            if (lane == 0) ht[wg] = s + bih[h] + bhh[h];
        }
    }
}

// ---------------- kernel 2: bf16 MFMA GEMM + tanh epilogue ----------------
// 128x128 tile, BK=64, 256 threads = 4 waves in 2x2, each wave 64x64 (4x4 MFMA).
// LDS 32 KB single buffer: A [0,16384), B [16384,32768). Rows are 64 bf16 =
// 128 B = 8 x 16B chunks; chunk slot = (q + (row>>1)) & 7 XOR swizzle so the
// ds_read_b128 fragment reads are only 2-way bank aliased (free, m136).
// Staging via global_load_lds width=16 with the inverse swizzle pre-applied to
// the per-lane GLOBAL address (LDS dest stays linear, as GLDS requires).
#define GLDS16(gp, lp) \
    __builtin_amdgcn_global_load_lds((const __attribute__((address_space(1))) void*)(gp), \
                                     (__attribute__((address_space(3))) void*)(lp), 16, 0, 0)

__global__ __launch_bounds__(256) void gemm_tanh_kernel(
    const unsigned short* __restrict__ A,   // [32768,1024] bf16 (X)
    const unsigned short* __restrict__ Bm,  // [1024,1024]  bf16 (W_ih, row n K-contig)
    const float* __restrict__ ht,           // [16,1024]
    float* __restrict__ out)                // [32768,1024] fp32
{
    __shared__ __align__(16) char lds[32768];

    const int tid = threadIdx.x;
    const int w = tid >> 6, l = tid & 63;

    // XCD-corrected mapping (verified R1: FETCH 265->90 MB). bid round-robins
    // over 8 XCDs; give XCD x contiguous widx chunk [x*256, +256), n innermost:
    // A m-panel fetched once into that XCD's L2, reused by all 8 n-tiles;
    // W (2 MB bf16) L2-resident per XCD.
    const int bid  = blockIdx.x;
    const int widx = (bid & 7) * 256 + (bid >> 3);
    const int tile_m = widx >> 3;      // 0..255
    const int tile_n = widx & 7;       // 0..7
    const int m0 = tile_m << 7, n0 = tile_n << 7;

    // ---- staging addresses: 4 A-instr + 4 B-instr per thread per K-iter ----
    // instr j of wave w covers tile rows [(w*4+j)*8, +8): lane l -> row +(l>>3),
    // 16B slot (l&7). Slot s holds global chunk qg = (s - (row>>1)) & 7.
    const unsigned short* gA[4];
    const unsigned short* gB[4];
    char* lA[4];
    char* lB[4];
#pragma unroll
    for (int j = 0; j < 4; ++j) {
        int r  = (w * 4 + j) * 8 + (l >> 3);
        int s  = l & 7;
        int qg = (s - ((r >> 1) & 7)) & 7;
        gA[j] = A  + (long long)(m0 + r) * K_TOT + qg * 8;
        gB[j] = Bm + (long long)(n0 + r) * K_TOT + qg * 8;
        lA[j] = lds + (w * 4 + j) * 1024;          // wave-uniform; HW adds lane*16
        lB[j] = lds + 16384 + (w * 4 + j) * 1024;
    }

    // ---- fragment read offsets ----
    // lane (lm = l&15, q = l>>4) reads row rr, logical k-chunk (q + 4*sh),
    // at swizzled slot ((q + 4*sh) + (rr>>1)) & 7.
    const int wm = w & 1, wn = w >> 1;       // 2x2 wave grid
    const int lm = l & 15, q = l >> 4;
    int offA[4][2], offB[4][2];
#pragma unroll
    for (int t = 0; t < 4; ++t) {
#pragma unroll
        for (int sh = 0; sh < 2; ++sh) {
            int rr = wm * 64 + t * 16 + lm;
            offA[t][sh] = rr * 128 + (((q + 4 * sh + ((rr >> 1) & 7)) & 7) << 4);
            int nn = wn * 64 + t * 16 + lm;
            offB[t][sh] = 16384 + nn * 128 + (((q + 4 * sh + ((nn >> 1) & 7)) & 7) << 4);
        }
    }

    f32x4 acc[4][4];
#pragma unroll
    for (int i = 0; i < 4; ++i)
#pragma unroll
        for (int j = 0; j < 4; ++j)
            acc[i][j] = (f32x4){0.f, 0.f, 0.f, 0.f};

    for (int k0 = 0; k0 < K_TOT; k0 += 64) {
#pragma unroll
        for (int j = 0; j < 4; ++j) {
            GLDS16(gA[j] + k0, lA[j]);
            GLDS16(gB[j] + k0, lB[j]);
        }
        __syncthreads();   // compiler drains vmcnt before s_barrier

        // sh = 0 half (k0 .. k0+31)
        {
            short8 af[4], bfr[4];
#pragma unroll
            for (int t = 0; t < 4; ++t) {
                af[t]  = *(const short8*)(lds + offA[t][0]);
                bfr[t] = *(const short8*)(lds + offB[t][0]);
            }
#pragma unroll
            for (int mt = 0; mt < 4; ++mt)
#pragma unroll
                for (int nt = 0; nt < 4; ++nt)
                    acc[mt][nt] = __builtin_amdgcn_mfma_f32_16x16x32_bf16(
                        af[mt], bfr[nt], acc[mt][nt], 0, 0, 0);
        }
        // sh = 1 half (k0+32 .. k0+63)
        {
            short8 af[4], bfr[4];
#pragma unroll
            for (int t = 0; t < 4; ++t) {
                af[t]  = *(const short8*)(lds + offA[t][1]);
                bfr[t] = *(const short8*)(lds + offB[t][1]);
            }
#pragma unroll
            for (int mt = 0; mt < 4; ++mt)
#pragma unroll
                for (int nt = 0; nt < 4; ++nt)
                    acc[mt][nt] = __builtin_amdgcn_mfma_f32_16x16x32_bf16(
                        af[mt], bfr[nt], acc[mt][nt], 0, 0, 0);
        }
        __syncthreads();
    }

    // ---- epilogue: out = tanh(acc + h_term[b, n]) ----
    // C/D layout: col = lane&15 (n), row = (lane>>4)*4 + reg (m). [m89-verified]
    const int b = tile_m >> 4;   // 16 m-tiles per batch element
    float htv[4];
#pragma unroll
    for (int nt = 0; nt < 4; ++nt)
        htv[nt] = ht[b * 1024 + n0 + wn * 64 + nt * 16 + lm];

#pragma unroll
    for (int mt = 0; mt < 4; ++mt) {
#pragma unroll
        for (int nt = 0; nt < 4; ++nt) {
            int n = n0 + wn * 64 + nt * 16 + lm;
#pragma unroll
            for (int r = 0; r < 4; ++r) {
                int m = m0 + wm * 64 + mt * 16 + q * 4 + r;
                float z = acc[mt][nt][r] + htv[nt];
                out[(long long)m * N_TOT + n] = fast_tanh(z);
            }
        }
    }
}

extern "C" void kernel_launch(void* const* d_in, const int* in_sizes, int n_in,
                              void* d_out, int out_size, void* d_ws, size_t ws_size,
                              hipStream_t stream) {
    const float* x    = (const float*)d_in[0];   // [16,2048,1024]
    const float* hx   = (const float*)d_in[1];   // [16,1024]
    const float* wih  = (const float*)d_in[2];   // [1024,1024]
    const float* whh  = (const float*)d_in[3];   // [1024,1024]
    const float* bih  = (const float*)d_in[4];   // [1024]
    const float* bhh  = (const float*)d_in[5];   // [1024]
    float* out = (float*)d_out;

    unsigned short* xbf = (unsigned short*)((char*)d_ws + WS_XBF_OFF);
    unsigned short* wbf = (unsigned short*)((char*)d_ws + WS_WBF_OFF);
    float*          htp = (float*)((char*)d_ws + WS_HT_OFF);

    // prep: X/W convert (blocks 0..2047) + h_term (blocks 2048..4095)
    prep_kernel<<<4096, 256, 0, stream>>>(x, wih, hx, whh, bih, bhh, xbf, wbf, htp);
    // GEMM + tanh: 256 m-tiles x 8 n-tiles, XCD-remapped
    gemm_tanh_kernel<<<2048, 256, 0, stream>>>(xbf, wbf, htp, out);
}

// Round 6
// 330.221 us; speedup vs baseline: 1.1678x; 1.0016x over previous
//
#include <hip/hip_runtime.h>
#include <hip/hip_bf16.h>
#include <stdint.h>

// Problem: B=16, S=2048, I=1024, H=1024  (all fp32 in/out)
// out[b,s,h] = tanh( sum_i x[b,s,i]*W_ih[h,i] + b_ih[h] + sum_k hx[b,k]*W_hh[h,k] + b_hh[h] )
// M = B*S = 32768, N = H = 1024, K = I = 1024.
//
// v6: round-0 verified LDS geometry (BK=32, 64B rows, 4-slot XOR swizzle ->
// 0 bank conflicts measured) + XCD-corrected mapping (FETCH 265->66 MB,
// verified) + NEW: minimum 2-phase pipeline (T3 recipe): double-buffered LDS
// (2 x 16 KB), STAGE(k+1) issued at ITER START before ds_read+MFMA of tile k,
// ONE __syncthreads per iter. The barrier's vmcnt(0) drain now waits on loads
// issued ~400 cycles earlier (covered by compute) instead of just-issued ones.
// Round-5 lesson: BK=64's 128B rows alias banks (row*128/4 % 32 == 0) ->
// 8.4M conflict cycles; BK=32's 64B rows rotate banks by 16/row (measured 0).

#define M_TOT 32768
#define N_TOT 1024
#define K_TOT 1024

typedef short short8 __attribute__((ext_vector_type(8)));   // 8 bf16 (4 VGPRs)
typedef float f32x4  __attribute__((ext_vector_type(4)));   // 4 fp32 acc

// ---- workspace layout (bytes) ----
// [0, 67108864)            X_bf   : 33554432 bf16
// [67108864, 69206016)     W_bf   : 1048576 bf16
// [69206016, 69271552)     h_term : 16384 fp32
#define WS_XBF_OFF   0
#define WS_WBF_OFF   67108864
#define WS_HT_OFF    69206016

__device__ __forceinline__ unsigned short f32_to_bf16_rne(float f) {
    union { float f; unsigned int u; } v; v.f = f;
    unsigned int u = v.u;
    unsigned int r = u + 0x7fffu + ((u >> 16) & 1u);
    return (unsigned short)(r >> 16);
}

__device__ __forceinline__ float fast_tanh(float z) {
    // tanh(z) = 1 - 2/(exp(2z)+1); __expf -> v_exp_f32. Saturates at +-inf.
    float e = __expf(2.0f * z);
    return 1.0f - 2.0f / (e + 1.0f);
}

// ---------------- kernel 1: prep = X/W convert + h_term, one launch ----------------
// blocks [0, 2048): grid-stride fp32->bf16 convert of X then W_ih
// blocks [2048, 4096): h_term; each wave does 2 dot products (16384 total)
__global__ void prep_kernel(const float* __restrict__ x,
                            const float* __restrict__ wih,
                            const float* __restrict__ hx,
                            const float* __restrict__ whh,
                            const float* __restrict__ bih,
                            const float* __restrict__ bhh,
                            unsigned short* __restrict__ xbf,
                            unsigned short* __restrict__ wbf,
                            float* __restrict__ ht) {
    if (blockIdx.x < 2048) {
        const int NXV = 33554432 / 8;  // vec8 groups in X
        const int NWV = 1048576 / 8;   // vec8 groups in W_ih
        const int stride = 2048 * 256;
        for (int v = blockIdx.x * 256 + threadIdx.x; v < NXV + NWV; v += stride) {
            const float* src; unsigned short* dst; long long base;
            if (v < NXV) { src = x;   dst = xbf; base = (long long)v * 8; }
            else         { src = wih; dst = wbf; base = (long long)(v - NXV) * 8; }
            float4 a = *(const float4*)(src + base);
            float4 b = *(const float4*)(src + base + 4);
            union { unsigned short s[8]; uint4 u; } o;
            o.s[0] = f32_to_bf16_rne(a.x); o.s[1] = f32_to_bf16_rne(a.y);
            o.s[2] = f32_to_bf16_rne(a.z); o.s[3] = f32_to_bf16_rne(a.w);
            o.s[4] = f32_to_bf16_rne(b.x); o.s[5] = f32_to_bf16_rne(b.y);
            o.s[6] = f32_to_bf16_rne(b.z); o.s[7] = f32_to_bf16_rne(b.w);
            *(uint4*)(dst + base) = o.u;
        }
    } else {
        int lane = threadIdx.x & 63;
        int w    = threadIdx.x >> 6;
        int wg_base = (blockIdx.x - 2048) * 8 + w * 2;
#pragma unroll
        for (int d = 0; d < 2; ++d) {
            int wg = wg_base + d;                 // 0..16383
            int b = wg >> 10, h = wg & 1023;
            const float* hr = hx  + (long long)b * 1024;
            const float* wr = whh + (long long)h * 1024;
            float s = 0.f;
#pragma unroll
            for (int p = 0; p < 4; ++p) {
                int idx = p * 256 + lane * 4;
                float4 a = *(const float4*)(hr + idx);
                float4 c = *(const float4*)(wr + idx);
                s += a.x * c.x + a.y * c.y + a.z * c.z + a.w * c.w;
            }
#pragma unroll
            for (int dd = 32; dd > 0; dd >>= 1) s += __shfl_down(s, dd, 64);
            if (lane == 0) ht[wg] = s + bih[h] + bhh[h];
        }
    }
}

// ---------------- kernel 2: bf16 MFMA GEMM + tanh epilogue ----------------
// 128x128 tile, BK=32, 256 threads = 4 waves in 2x2, each wave 64x64 (4x4 MFMA
// 16x16x32). LDS: TWO buffers of 16 KB; buffer p at [p*16384): A [0,8192),
// B [8192,16384). Rows are 32 bf16 = 64 B = 4 x 16B chunks; chunk slot =
// (q + (row>>1)) & 3 XOR swizzle (round-0 verified: 0 bank conflicts).
// Staging via global_load_lds width=16 with the inverse swizzle pre-applied
// to the per-lane GLOBAL address (LDS dest stays linear, as GLDS requires).
#define GLDS16(gp, lp) \
    __builtin_amdgcn_global_load_lds((const __attribute__((address_space(1))) void*)(gp), \
                                     (__attribute__((address_space(3))) void*)(lp), 16, 0, 0)

// One K-iteration: optionally STAGE tile (KNEXT/32) into buf[P^1] FIRST, then
// ds_read + 16 MFMA from buf[P], then one barrier. The barrier's vmcnt(0)
// drain waits on loads that have had the whole compute phase to complete.
#define KITER(KNEXT, P, STAGE)                                                 \
  {                                                                            \
    if (STAGE) {                                                               \
      GLDS16(gA0 + (KNEXT), lA0 + ((P) ^ 1) * 16384);                          \
      GLDS16(gA1 + (KNEXT), lA1 + ((P) ^ 1) * 16384);                          \
      GLDS16(gB0 + (KNEXT), lB0 + ((P) ^ 1) * 16384);                          \
      GLDS16(gB1 + (KNEXT), lB1 + ((P) ^ 1) * 16384);                          \
    }                                                                          \
    {                                                                          \
      const char* lb = lds + (P) * 16384;                                      \
      short8 af[4], bfr[4];                                                    \
      _Pragma("unroll")                                                        \
      for (int t4 = 0; t4 < 4; ++t4) {                                         \
        af[t4]  = *(const short8*)(lb + offA[t4]);                             \
        bfr[t4] = *(const short8*)(lb + offB[t4]);                             \
      }                                                                        \
      _Pragma("unroll")                                                        \
      for (int mt = 0; mt < 4; ++mt)                                           \
        _Pragma("unroll")                                                      \
        for (int nt = 0; nt < 4; ++nt)                                         \
          acc[mt][nt] = __builtin_amdgcn_mfma_f32_16x16x32_bf16(               \
              af[mt], bfr[nt], acc[mt][nt], 0, 0, 0);                          \
    }                                                                          \
    __syncthreads();                                                           \
  }

__global__ __launch_bounds__(256) void gemm_tanh_kernel(
    const unsigned short* __restrict__ A,   // [32768,1024] bf16 (X)
    const unsigned short* __restrict__ Bm,  // [1024,1024]  bf16 (W_ih, row n K-contig)
    const float* __restrict__ ht,           // [16,1024]
    float* __restrict__ out)                // [32768,1024] fp32
{
    __shared__ __align__(16) char lds[32768];

    const int tid = threadIdx.x;
    const int w = tid >> 6, l = tid & 63;

    // XCD-corrected mapping (verified: FETCH 265->66 MB). bid round-robins
    // over 8 XCDs; XCD x gets contiguous widx chunk [x*256, +256), n innermost:
    // A m-panel fetched once into that XCD's L2, reused by all 8 n-tiles;
    // W (2 MB bf16) L2-resident per XCD.
    const int bid  = blockIdx.x;
    const int widx = (bid & 7) * 256 + (bid >> 3);
    const int tile_m = widx >> 3;      // 0..255
    const int tile_n = widx & 7;       // 0..7
    const int m0 = tile_m << 7, n0 = tile_n << 7;

    // ---- staging addresses (2 A-instr + 2 B-instr per thread per K-iter) ----
    // wave w, instr j covers tile rows [(w*2+j)*16, +16); lane l -> row +(l>>2),
    // 16B slot (l&3). Slot s holds global chunk qg = (s - (row>>1)) & 3
    // (inverse of the read swizzle).
    const int r0 = (w * 2 + 0) * 16 + (l >> 2);
    const int r1 = (w * 2 + 1) * 16 + (l >> 2);
    const int slot = l & 3;
    const int qg0 = (slot - (r0 >> 1)) & 3;
    const int qg1 = (slot - (r1 >> 1)) & 3;
    const unsigned short* gA0 = A  + (long long)(m0 + r0) * K_TOT + qg0 * 8;
    const unsigned short* gA1 = A  + (long long)(m0 + r1) * K_TOT + qg1 * 8;
    const unsigned short* gB0 = Bm + (long long)(n0 + r0) * K_TOT + qg0 * 8;
    const unsigned short* gB1 = Bm + (long long)(n0 + r1) * K_TOT + qg1 * 8;
    char* lA0 = lds + (w * 2 + 0) * 1024;          // wave-uniform; HW adds lane*16
    char* lA1 = lds + (w * 2 + 1) * 1024;
    char* lB0 = lds + 8192 + (w * 2 + 0) * 1024;
    char* lB1 = lds + 8192 + (w * 2 + 1) * 1024;

    // ---- fragment read offsets (within one 16 KB buffer) ----
    const int wm = w & 1, wn = w >> 1;       // 2x2 wave grid
    const int lm = l & 15, q = l >> 4;       // MFMA operand: row = lm, k-chunk = q
    int offA[4], offB[4];
#pragma unroll
    for (int t = 0; t < 4; ++t) {
        int rr = wm * 64 + t * 16 + lm;
        offA[t] = rr * 64 + (((q + (rr >> 1)) & 3) << 4);
        int nn = wn * 64 + t * 16 + lm;
        offB[t] = 8192 + nn * 64 + (((q + (nn >> 1)) & 3) << 4);
    }

    f32x4 acc[4][4];
#pragma unroll
    for (int i = 0; i < 4; ++i)
#pragma unroll
        for (int j = 0; j < 4; ++j)
            acc[i][j] = (f32x4){0.f, 0.f, 0.f, 0.f};

    // ---- prologue: stage tile 0 into buf0 ----
    GLDS16(gA0, lA0);
    GLDS16(gA1, lA1);
    GLDS16(gB0, lB0);
    GLDS16(gB1, lB1);
    __syncthreads();

    // ---- main loop: 32 K-iters; iter i computes buf(i&1), stages buf(i&1)^1 ----
    // 30 pipelined iters (x2 unroll for parity), then iter 30 (stages 31),
    // then iter 31 (no stage).
    for (int i = 0; i < 30; i += 2) {
        KITER((i + 1) * 32, 0, true);
        KITER((i + 2) * 32, 1, true);
    }
    KITER(31 * 32, 0, true);    // iter 30: compute buf0, stage k=31 -> buf1
    KITER(0,       1, false);   // iter 31: compute buf1, no stage

    // ---- epilogue: out = tanh(acc + h_term[b, n]) ----
    // C/D layout: col = lane&15 (n), row = (lane>>4)*4 + reg (m). [m89-verified]
    const int b = tile_m >> 4;   // 16 m-tiles per batch element
    float htv[4];
#pragma unroll
    for (int nt = 0; nt < 4; ++nt)
        htv[nt] = ht[b * 1024 + n0 + wn * 64 + nt * 16 + lm];

#pragma unroll
    for (int mt = 0; mt < 4; ++mt) {
#pragma unroll
        for (int nt = 0; nt < 4; ++nt) {
            int n = n0 + wn * 64 + nt * 16 + lm;
#pragma unroll
            for (int r = 0; r < 4; ++r) {
                int m = m0 + wm * 64 + mt * 16 + q * 4 + r;
                float z = acc[mt][nt][r] + htv[nt];
                out[(long long)m * N_TOT + n] = fast_tanh(z);
            }
        }
    }
}

extern "C" void kernel_launch(void* const* d_in, const int* in_sizes, int n_in,
                              void* d_out, int out_size, void* d_ws, size_t ws_size,
                              hipStream_t stream) {
    const float* x    = (const float*)d_in[0];   // [16,2048,1024]
    const float* hx   = (const float*)d_in[1];   // [16,1024]
    const float* wih  = (const float*)d_in[2];   // [1024,1024]
    const float* whh  = (const float*)d_in[3];   // [1024,1024]
    const float* bih  = (const float*)d_in[4];   // [1024]
    const float* bhh  = (const float*)d_in[5];   // [1024]
    float* out = (float*)d_out;

    unsigned short* xbf = (unsigned short*)((char*)d_ws + WS_XBF_OFF);
    unsigned short* wbf = (unsigned short*)((char*)d_ws + WS_WBF_OFF);
    float*          htp = (float*)((char*)d_ws + WS_HT_OFF);

    // prep: X/W convert (blocks 0..2047) + h_term (blocks 2048..4095)
    prep_kernel<<<4096, 256, 0, stream>>>(x, wih, hx, whh, bih, bhh, xbf, wbf, htp);
    // GEMM + tanh: 256 m-tiles x 8 n-tiles, XCD-remapped
    gemm_tanh_kernel<<<2048, 256, 0, stream>>>(xbf, wbf, htp, out);
}

// Round 7
// 325.633 us; speedup vs baseline: 1.1843x; 1.0141x over previous
//
#include <hip/hip_runtime.h>
#include <hip/hip_bf16.h>
#include <stdint.h>

// Problem: B=16, S=2048, I=1024, H=1024  (all fp32 in/out)
// out[b,s,h] = tanh( sum_i x[b,s,i]*W_ih[h,i] + b_ih[h] + sum_k hx[b,k]*W_hh[h,k] + b_hh[h] )
// M = B*S = 32768, N = H = 1024, K = I = 1024.
//
// v7: R6 skeleton (BK=32, 64B rows, 0-conflict XOR swizzle, GLDS both operands,
// XCD-corrected mapping: FETCH 66 MB verified) + NEW: 2-deep pipeline.
// Triple-buffered LDS (3 x 16 KB), iter k stages tile k+2, computes tile k,
// then s_waitcnt vmcnt(4) (retires exactly stage(k+1), issued 2 compute-phases
// earlier ~700cy -> covers HBM) + ONE raw s_barrier. No ds_writes -> no lgkm
// in the loop; ds_reads are consumed in-iter (compiler waits before MFMA).
// R6 lesson: stage-at-start under __syncthreads only gives ~1 phase of cover
// (106 us); R2/R3's counted-vmcnt was confounded by reg-staged A.

#define M_TOT 32768
#define N_TOT 1024
#define K_TOT 1024

typedef short short8 __attribute__((ext_vector_type(8)));   // 8 bf16 (4 VGPRs)
typedef float f32x4  __attribute__((ext_vector_type(4)));   // 4 fp32 acc

// ---- workspace layout (bytes) ----
// [0, 67108864)            X_bf   : 33554432 bf16
// [67108864, 69206016)     W_bf   : 1048576 bf16
// [69206016, 69271552)     h_term : 16384 fp32
#define WS_XBF_OFF   0
#define WS_WBF_OFF   67108864
#define WS_HT_OFF    69206016

__device__ __forceinline__ unsigned short f32_to_bf16_rne(float f) {
    union { float f; unsigned int u; } v; v.f = f;
    unsigned int u = v.u;
    unsigned int r = u + 0x7fffu + ((u >> 16) & 1u);
    return (unsigned short)(r >> 16);
}

__device__ __forceinline__ float fast_tanh(float z) {
    // tanh(z) = 1 - 2/(exp(2z)+1); __expf -> v_exp_f32. Saturates at +-inf.
    float e = __expf(2.0f * z);
    return 1.0f - 2.0f / (e + 1.0f);
}

// ---------------- kernel 1: prep = X/W convert + h_term, one launch ----------------
__global__ void prep_kernel(const float* __restrict__ x,
                            const float* __restrict__ wih,
                            const float* __restrict__ hx,
                            const float* __restrict__ whh,
                            const float* __restrict__ bih,
                            const float* __restrict__ bhh,
                            unsigned short* __restrict__ xbf,
                            unsigned short* __restrict__ wbf,
                            float* __restrict__ ht) {
    if (blockIdx.x < 2048) {
        const int NXV = 33554432 / 8;  // vec8 groups in X
        const int NWV = 1048576 / 8;   // vec8 groups in W_ih
        const int stride = 2048 * 256;
        for (int v = blockIdx.x * 256 + threadIdx.x; v < NXV + NWV; v += stride) {
            const float* src; unsigned short* dst; long long base;
            if (v < NXV) { src = x;   dst = xbf; base = (long long)v * 8; }
            else         { src = wih; dst = wbf; base = (long long)(v - NXV) * 8; }
            float4 a = *(const float4*)(src + base);
            float4 b = *(const float4*)(src + base + 4);
            union { unsigned short s[8]; uint4 u; } o;
            o.s[0] = f32_to_bf16_rne(a.x); o.s[1] = f32_to_bf16_rne(a.y);
            o.s[2] = f32_to_bf16_rne(a.z); o.s[3] = f32_to_bf16_rne(a.w);
            o.s[4] = f32_to_bf16_rne(b.x); o.s[5] = f32_to_bf16_rne(b.y);
            o.s[6] = f32_to_bf16_rne(b.z); o.s[7] = f32_to_bf16_rne(b.w);
            *(uint4*)(dst + base) = o.u;
        }
    } else {
        int lane = threadIdx.x & 63;
        int w    = threadIdx.x >> 6;
        int wg_base = (blockIdx.x - 2048) * 8 + w * 2;
#pragma unroll
        for (int d = 0; d < 2; ++d) {
            int wg = wg_base + d;                 // 0..16383
            int b = wg >> 10, h = wg & 1023;
            const float* hr = hx  + (long long)b * 1024;
            const float* wr = whh + (long long)h * 1024;
            float s = 0.f;
#pragma unroll
            for (int p = 0; p < 4; ++p) {
                int idx = p * 256 + lane * 4;
                float4 a = *(const float4*)(hr + idx);
                float4 c = *(const float4*)(wr + idx);
                s += a.x * c.x + a.y * c.y + a.z * c.z + a.w * c.w;
            }
#pragma unroll
            for (int dd = 32; dd > 0; dd >>= 1) s += __shfl_down(s, dd, 64);
            if (lane == 0) ht[wg] = s + bih[h] + bhh[h];
        }
    }
}

// ---------------- kernel 2: bf16 MFMA GEMM + tanh epilogue ----------------
// 128x128 tile, BK=32, 256 threads = 4 waves in 2x2, each wave 64x64 (4x4 MFMA
// 16x16x32). LDS: THREE buffers of 16 KB; buffer p at [p*16384): A [0,8192),
// B [8192,16384). Rows are 32 bf16 = 64 B = 4 x 16B chunks; chunk slot =
// (q + (row>>1)) & 3 XOR swizzle (verified 0 bank conflicts).
// Staging via global_load_lds width=16 with the inverse swizzle pre-applied
// to the per-lane GLOBAL address (LDS dest stays linear, as GLDS requires).
#define GLDS16(gp, lp) \
    __builtin_amdgcn_global_load_lds((const __attribute__((address_space(1))) void*)(gp), \
                                     (__attribute__((address_space(3))) void*)(lp), 16, 0, 0)

// One K-iteration at index T: stage tile T+2 into buf PS, compute buf PC,
// s_waitcnt vmcnt(NW) (NW=4: retires exactly stage(T+1); NW=0: drain),
// one raw s_barrier. Compile-only "" memory fence after the barrier keeps
// the next iter's GLDS from hoisting above it (so the vmcnt count is exact).
#define KITER(T, PC, PS, DOSTAGE, NW)                                          \
  {                                                                            \
    if (DOSTAGE) {                                                             \
      const int kk = ((T) + 2) * 32;                                           \
      GLDS16(gA0 + kk, lA0 + (PS) * 16384);                                    \
      GLDS16(gA1 + kk, lA1 + (PS) * 16384);                                    \
      GLDS16(gB0 + kk, lB0 + (PS) * 16384);                                    \
      GLDS16(gB1 + kk, lB1 + (PS) * 16384);                                    \
    }                                                                          \
    {                                                                          \
      const char* lb = lds + (PC) * 16384;                                     \
      short8 af[4], bfr[4];                                                    \
      _Pragma("unroll")                                                        \
      for (int t4 = 0; t4 < 4; ++t4) {                                         \
        af[t4]  = *(const short8*)(lb + offA[t4]);                             \
        bfr[t4] = *(const short8*)(lb + offB[t4]);                             \
      }                                                                        \
      _Pragma("unroll")                                                        \
      for (int mt = 0; mt < 4; ++mt)                                           \
        _Pragma("unroll")                                                      \
        for (int nt = 0; nt < 4; ++nt)                                         \
          acc[mt][nt] = __builtin_amdgcn_mfma_f32_16x16x32_bf16(               \
              af[mt], bfr[nt], acc[mt][nt], 0, 0, 0);                          \
    }                                                                          \
    asm volatile("s_waitcnt vmcnt(" #NW ")" ::: "memory");                     \
    __builtin_amdgcn_s_barrier();                                              \
    asm volatile("" ::: "memory");                                             \
  }

__global__ __launch_bounds__(256) void gemm_tanh_kernel(
    const unsigned short* __restrict__ A,   // [32768,1024] bf16 (X)
    const unsigned short* __restrict__ Bm,  // [1024,1024]  bf16 (W_ih, row n K-contig)
    const float* __restrict__ ht,           // [16,1024]
    float* __restrict__ out)                // [32768,1024] fp32
{
    __shared__ __align__(16) char lds[49152];

    const int tid = threadIdx.x;
    const int w = tid >> 6, l = tid & 63;

    // XCD-corrected mapping (verified: FETCH 265->66 MB).
    const int bid  = blockIdx.x;
    const int widx = (bid & 7) * 256 + (bid >> 3);
    const int tile_m = widx >> 3;      // 0..255
    const int tile_n = widx & 7;       // 0..7
    const int m0 = tile_m << 7, n0 = tile_n << 7;

    // ---- staging addresses (2 A-instr + 2 B-instr per thread per K-iter) ----
    // wave w, instr j covers tile rows [(w*2+j)*16, +16); lane l -> row +(l>>2),
    // 16B slot (l&3). Slot s holds global chunk qg = (s - (row>>1)) & 3.
    const int r0 = (w * 2 + 0) * 16 + (l >> 2);
    const int r1 = (w * 2 + 1) * 16 + (l >> 2);
    const int slot = l & 3;
    const int qg0 = (slot - (r0 >> 1)) & 3;
    const int qg1 = (slot - (r1 >> 1)) & 3;
    const unsigned short* gA0 = A  + (long long)(m0 + r0) * K_TOT + qg0 * 8;
    const unsigned short* gA1 = A  + (long long)(m0 + r1) * K_TOT + qg1 * 8;
    const unsigned short* gB0 = Bm + (long long)(n0 + r0) * K_TOT + qg0 * 8;
    const unsigned short* gB1 = Bm + (long long)(n0 + r1) * K_TOT + qg1 * 8;
    char* lA0 = lds + (w * 2 + 0) * 1024;          // wave-uniform; HW adds lane*16
    char* lA1 = lds + (w * 2 + 1) * 1024;
    char* lB0 = lds + 8192 + (w * 2 + 0) * 1024;
    char* lB1 = lds + 8192 + (w * 2 + 1) * 1024;

    // ---- fragment read offsets (within one 16 KB buffer) ----
    const int wm = w & 1, wn = w >> 1;       // 2x2 wave grid
    const int lm = l & 15, q = l >> 4;       // MFMA operand: row = lm, k-chunk = q
    int offA[4], offB[4];
#pragma unroll
    for (int t = 0; t < 4; ++t) {
        int rr = wm * 64 + t * 16 + lm;
        offA[t] = rr * 64 + (((q + (rr >> 1)) & 3) << 4);
        int nn = wn * 64 + t * 16 + lm;
        offB[t] = 8192 + nn * 64 + (((q + (nn >> 1)) & 3) << 4);
    }

    f32x4 acc[4][4];
#pragma unroll
    for (int i = 0; i < 4; ++i)
#pragma unroll
        for (int j = 0; j < 4; ++j)
            acc[i][j] = (f32x4){0.f, 0.f, 0.f, 0.f};

    // ---- prologue: stage tile0 -> buf0, tile1 -> buf1 ----
    GLDS16(gA0 +  0, lA0);          GLDS16(gA1 +  0, lA1);
    GLDS16(gB0 +  0, lB0);          GLDS16(gB1 +  0, lB1);
    GLDS16(gA0 + 32, lA0 + 16384);  GLDS16(gA1 + 32, lA1 + 16384);
    GLDS16(gB0 + 32, lB0 + 16384);  GLDS16(gB1 + 32, lB1 + 16384);
    asm volatile("s_waitcnt vmcnt(4)" ::: "memory");  // tile0 landed; tile1 in flight
    __builtin_amdgcn_s_barrier();
    asm volatile("" ::: "memory");

    // ---- main loop: iters 0..29 (x3 unroll for buffer parity), then tail ----
    // iter k: stage tile k+2 -> buf (k+2)%3, compute buf k%3, vmcnt(4)
    // retires stage(k+1) (issued at iter k-1: ~2 compute phases of cover).
    for (int i = 0; i < 30; i += 3) {
        KITER(i + 0, 0, 2, true, 4);
        KITER(i + 1, 1, 0, true, 4);
        KITER(i + 2, 2, 1, true, 4);
    }
    KITER(30, 0, 0, false, 0);   // compute buf0; vmcnt(0) retires stage(31)
    // iter 31: compute buf1, nothing outstanding, no barrier needed
    {
        const char* lb = lds + 1 * 16384;
        short8 af[4], bfr[4];
#pragma unroll
        for (int t4 = 0; t4 < 4; ++t4) {
            af[t4]  = *(const short8*)(lb + offA[t4]);
            bfr[t4] = *(const short8*)(lb + offB[t4]);
        }
#pragma unroll
        for (int mt = 0; mt < 4; ++mt)
#pragma unroll
            for (int nt = 0; nt < 4; ++nt)
                acc[mt][nt] = __builtin_amdgcn_mfma_f32_16x16x32_bf16(
                    af[mt], bfr[nt], acc[mt][nt], 0, 0, 0);
    }

    // ---- epilogue: out = tanh(acc + h_term[b, n]) ----
    // C/D layout: col = lane&15 (n), row = (lane>>4)*4 + reg (m). [m89-verified]
    const int b = tile_m >> 4;   // 16 m-tiles per batch element
    float htv[4];
#pragma unroll
    for (int nt = 0; nt < 4; ++nt)
        htv[nt] = ht[b * 1024 + n0 + wn * 64 + nt * 16 + lm];

#pragma unroll
    for (int mt = 0; mt < 4; ++mt) {
#pragma unroll
        for (int nt = 0; nt < 4; ++nt) {
            int n = n0 + wn * 64 + nt * 16 + lm;
#pragma unroll
            for (int r = 0; r < 4; ++r) {
                int m = m0 + wm * 64 + mt * 16 + q * 4 + r;
                float z = acc[mt][nt][r] + htv[nt];
                out[(long long)m * N_TOT + n] = fast_tanh(z);
            }
        }
    }
}

extern "C" void kernel_launch(void* const* d_in, const int* in_sizes, int n_in,
                              void* d_out, int out_size, void* d_ws, size_t ws_size,
                              hipStream_t stream) {
    const float* x    = (const float*)d_in[0];   // [16,2048,1024]
    const float* hx   = (const float*)d_in[1];   // [16,1024]
    const float* wih  = (const float*)d_in[2];   // [1024,1024]
    const float* whh  = (const float*)d_in[3];   // [1024,1024]
    const float* bih  = (const float*)d_in[4];   // [1024]
    const float* bhh  = (const float*)d_in[5];   // [1024]
    float* out = (float*)d_out;

    unsigned short* xbf = (unsigned short*)((char*)d_ws + WS_XBF_OFF);
    unsigned short* wbf = (unsigned short*)((char*)d_ws + WS_WBF_OFF);
    float*          htp = (float*)((char*)d_ws + WS_HT_OFF);

    // prep: X/W convert (blocks 0..2047) + h_term (blocks 2048..4095)
    prep_kernel<<<4096, 256, 0, stream>>>(x, wih, hx, whh, bih, bhh, xbf, wbf, htp);
    // GEMM + tanh: 256 m-tiles x 8 n-tiles, XCD-remapped
    gemm_tanh_kernel<<<2048, 256, 0, stream>>>(xbf, wbf, htp, out);
}